// Round 10
// baseline (1360.075 us; speedup 1.0000x reference)
//
#include <hip/hip_runtime.h>
#include <hip/hip_bf16.h>

namespace {

constexpr int B  = 32;
constexpr int L  = 100;
constexpr int S  = 501;
constexpr int DK = 64;
constexpr int DE = 128;

typedef __attribute__((ext_vector_type(8))) short short8v;   // 8 bf16 (4 VGPR)
typedef __attribute__((ext_vector_type(4))) float f32x4;
typedef unsigned int u32;

__device__ __forceinline__ float sigm(float x) {
    return __fdividef(1.0f, 1.0f + __expf(-x));
}
// fp32 -> bf16 with round-to-nearest-even
__device__ __forceinline__ unsigned short f2bf(float f) {
    u32 u = __float_as_uint(f);
    u += 0x7FFFu + ((u >> 16) & 1u);
    return (unsigned short)(u >> 16);
}

// ---------------- init: transpose weights (k-major) for pre/y, pred[:,0] ---
__global__ __launch_bounds__(256) void k_init(
    const float* __restrict__ W1, const float* __restrict__ W2,
    const float* __restrict__ W3, const float* __restrict__ W4,
    const float* __restrict__ W5,
    float* __restrict__ W1T, float* __restrict__ W2T, float* __restrict__ W3T,
    float* __restrict__ W4T, float* __restrict__ W5T,
    float* __restrict__ pred)
{
    const int idx = blockIdx.x * 256 + threadIdx.x;
    const int st  = gridDim.x * 256;
    for (int i = idx; i < 64 * 256; i += st) {
        int dd = i >> 8, kk = i & 255;
        W1T[kk * 64 + dd] = W1[i];
        W2T[kk * 64 + dd] = W2[i];
        W3T[kk * 64 + dd] = W3[i];
    }
    for (int i = idx; i < 64 * 192; i += st) {
        int dd = i / 192, kk = i % 192;
        W4T[kk * 64 + dd] = W4[i];
        W5T[kk * 64 + dd] = W5[i];
    }
    if (idx < B) pred[idx * L] = 0.0f;
}

// ---------------- all_learning = concat(e,at,a) @ W1^T + b1 ----------------
__global__ __launch_bounds__(256) void k_all_learning(
    const int* __restrict__ e_data, const int* __restrict__ a_data,
    const int* __restrict__ at_data,
    const float* __restrict__ e_embed, const float* __restrict__ at_embed,
    const float* __restrict__ W1T, const float* __restrict__ b1,
    float* __restrict__ allL)
{
    __shared__ float in_s[4][257];
    const int g = threadIdx.x >> 6;
    const int d = threadIdx.x & 63;
    const int row = blockIdx.x * 4 + g;
    const int e  = e_data[row];
    const int at = at_data[row];
    in_s[g][d]       = e_embed[(size_t)e * DE + d];
    in_s[g][64 + d]  = e_embed[(size_t)e * DE + 64 + d];
    in_s[g][128 + d] = at_embed[(size_t)at * DK + d];
    in_s[g][192 + d] = (float)a_data[row];
    __syncthreads();
    float acc = b1[d];
    #pragma unroll 8
    for (int k = 0; k < 256; ++k) acc += W1T[k * 64 + d] * in_s[g][k];
    allL[row * DK + d] = acc;
}

// ---------------- G2,G3 (non-recurrent parts), G4it, prey ------------------
__global__ __launch_bounds__(256) void k_pre(
    const int* __restrict__ e_data, const int* __restrict__ it_data,
    const float* __restrict__ e_embed, const float* __restrict__ it_embed,
    const float* __restrict__ allL,
    const float* __restrict__ W2T, const float* __restrict__ W3T,
    const float* __restrict__ W4T, const float* __restrict__ W5T,
    const float* __restrict__ b2, const float* __restrict__ b3,
    const float* __restrict__ b4, const float* __restrict__ b5,
    float* __restrict__ G2, float* __restrict__ G3,
    float* __restrict__ G4it, float* __restrict__ prey)
{
    __shared__ float lp[4][64], its[4][64], ln[4][64], ee[4][128];
    const int g = threadIdx.x >> 6;
    const int d = threadIdx.x & 63;
    const int row = blockIdx.x * 4 + g;
    const int t = row % L;
    lp[g][d]  = (t == 0) ? 0.0f : allL[(row - 1) * 64 + d];
    its[g][d] = it_embed[(size_t)it_data[row] * 64 + d];
    ln[g][d]  = allL[row * 64 + d];
    const int e = e_data[row];
    ee[g][d]      = e_embed[(size_t)e * DE + d];
    ee[g][64 + d] = e_embed[(size_t)e * DE + 64 + d];
    __syncthreads();
    float g2 = b2[d], g3 = b3[d], g4 = b4[d], py = b5[d];
    #pragma unroll 4
    for (int k = 0; k < 64; ++k) {
        const float l0 = lp[g][k], i0 = its[g][k], n0 = ln[g][k];
        g2 += W2T[k * 64 + d] * l0 + W2T[(64 + k) * 64 + d] * i0 + W2T[(128 + k) * 64 + d] * n0;
        g3 += W3T[k * 64 + d] * l0 + W3T[(64 + k) * 64 + d] * i0 + W3T[(128 + k) * 64 + d] * n0;
        g4 += W4T[(128 + k) * 64 + d] * i0;
        py += W5T[k * 64 + d] * ee[g][k] + W5T[(64 + k) * 64 + d] * ee[g][64 + k];
    }
    G2[row * 64 + d]   = g2;
    G3[row * 64 + d]   = g3;
    G4it[row * 64 + d] = g4;
    prey[row * 64 + d] = py;
}

// ---------------- persistent recurrence: one block per BATCH ---------------
// 32 blocks x 512 threads (8 waves). TWO barriers per step:
//   A: h_tilde partials (red) published (all waves -> wave 0)
//   B: LGs/Vs published (wave 0 -> all waves)
// All other LDS (hB, qQ) is wave-private by construction (wave w touches only
// rows 64w..64w+63), so no other sync is needed. q rows and G2/G3/G4 are
// software-pipelined one full step ahead (register-carried) so no global
// latency is exposed. h_tilde history stays in LDS; one bulk write at end.
__global__ __launch_bounds__(512, 1) void k_steps(
    const float* __restrict__ G2, const float* __restrict__ G3,
    const float* __restrict__ G4it,
    const float* __restrict__ W2T, const float* __restrict__ W3T,
    const float* __restrict__ W4T, const float* __restrict__ W4,
    const float* __restrict__ q_matrix, const int* __restrict__ e_data,
    const float* __restrict__ h0, float* __restrict__ hthist)
{
    __shared__ unsigned short hB[512 * 72];   // h mirror bf16, pad 72 (73728 B)
    __shared__ float qQ[2][512];              // q[e_t]/q[e_{t+1}]   (4096 B)
    __shared__ float2 w23S[64 * 64];          // paired {W2h,W3h}[k][d] (32768 B)
    __shared__ float  w4bS[64 * 64];          // W4b[k][d]          (16384 B)
    __shared__ float  htH[100 * 64];          // h_tilde history    (25600 B)
    __shared__ float  LGs[64], Vs[64], htS[64];
    __shared__ float  red[8 * 64];            // per-wave h_tilde partials
    __shared__ int    eRow[104];              // total ~155.8 KB

    const int tid = threadIdx.x;
    const int b   = blockIdx.x;
    const int l   = tid & 63;
    const int w   = tid >> 6;
    const int lm  = l & 15;
    const int lk  = l >> 4;

    // ---- one-time staging: gate weights (coalesced via k-major W*T) ----
    for (int i = tid; i < 4096; i += 512) {
        const int k = i >> 6, dd = i & 63;
        w23S[i] = make_float2(W2T[(192 + k) * 64 + dd], W3T[(192 + k) * 64 + dd]);
        w4bS[i] = W4T[(64 + k) * 64 + dd];
    }
    if (tid < L) eRow[tid] = e_data[b * L + tid];

    // ---- A-fragments: W4a[d][k] bf16, persistent in regs (round-9 layout) --
    short8v afr[4][2];
    #pragma unroll
    for (int dt = 0; dt < 4; ++dt)
        #pragma unroll
        for (int kc = 0; kc < 2; ++kc) {
            const float* src = W4 + (size_t)(dt * 16 + lm) * 192 + kc * 32 + lk * 8;
            union { unsigned short us[8]; short8v v; } u;
            #pragma unroll
            for (int j = 0; j < 8; ++j) u.us[j] = f2bf(src[j]);
            afr[dt][kc] = u.v;
        }

    // ---- h registers + bf16 LDS mirror ----
    f32x4 hreg[4][4];
    #pragma unroll
    for (int st = 0; st < 4; ++st) {
        const int s = (w * 4 + st) * 16 + lm;
        #pragma unroll
        for (int dt = 0; dt < 4; ++dt) {
            const int d0 = dt * 16 + lk * 4;
            f32x4 hv = {0.f, 0.f, 0.f, 0.f};
            if (s < S) hv = *(const f32x4*)(h0 + (size_t)s * 64 + d0);
            hreg[st][dt] = hv;
            const u32 lo = (u32)f2bf(hv.x) | ((u32)f2bf(hv.y) << 16);
            const u32 hi = (u32)f2bf(hv.z) | ((u32)f2bf(hv.w) << 16);
            *(uint2*)&hB[s * 72 + d0] = make_uint2(lo, hi);
        }
    }
    __syncthreads();                                 // eRow ready

    // ---- prologue: q[e_0] -> qQ[0]; prefetch q[e_1] + G[t=0] ----
    float qn_reg;
    {
        const float q0 = (tid < S) ? q_matrix[(size_t)eRow[0] * S + tid] : 0.f;
        qQ[0][tid] = q0;
        qn_reg = (tid < S) ? q_matrix[(size_t)eRow[1] * S + tid] : 0.f;
    }
    float g2v = 0.f, g3v = 0.f, g4v = 0.f;
    if (tid < 64) {
        g2v = G2[(b * L) * 64 + l];
        g3v = G3[(b * L) * 64 + l];
        g4v = G4it[(b * L) * 64 + l];
    }
    __syncthreads();                                 // qQ[0] ready

    // ---- h_tilde_0 partials -> red ----
    {
        f32x4 part[4];
        #pragma unroll
        for (int dt = 0; dt < 4; ++dt) part[dt] = f32x4{0.f, 0.f, 0.f, 0.f};
        #pragma unroll
        for (int st = 0; st < 4; ++st) {
            const int s = (w * 4 + st) * 16 + lm;
            const float qe = qQ[0][s];
            #pragma unroll
            for (int dt = 0; dt < 4; ++dt) part[dt] += qe * hreg[st][dt];
        }
        #pragma unroll
        for (int dt = 0; dt < 4; ++dt)
            #pragma unroll
            for (int i = 0; i < 4; ++i) {
                float v = part[dt][i];
                v += __shfl_xor(v, 1); v += __shfl_xor(v, 2);
                v += __shfl_xor(v, 4); v += __shfl_xor(v, 8);
                part[dt][i] = v;
            }
        if (lm == 0) {
            #pragma unroll
            for (int dt = 0; dt < 4; ++dt)
                *(f32x4*)&red[w * 64 + dt * 16 + lk * 4] = part[dt];
        }
    }
    __syncthreads();                                 // barrier A (t=0): red ready

    // ---------------- 99 steps ----------------
    for (int t = 0; t < L - 1; ++t) {
        const int cur = t & 1, nxt = cur ^ 1;

        // start phase (all waves): publish prefetched q, issue next q load,
        // read own hB rows for MFMA B-fragments.
        qQ[nxt][tid] = qn_reg;
        {
            const int tn = (t + 2 < L) ? t + 2 : L - 1;
            qn_reg = (tid < S) ? q_matrix[(size_t)eRow[tn] * S + tid] : 0.f;
        }
        short8v bfr[4][2];
        #pragma unroll
        for (int st = 0; st < 4; ++st) {
            const int s = (w * 4 + st) * 16 + lm;
            #pragma unroll
            for (int kc = 0; kc < 2; ++kc)
                bfr[st][kc] = *(const short8v*)&hB[s * 72 + kc * 32 + lk * 8];
        }

        // wave-0 serial gate chain (wave-internal ordering only, no barriers)
        if (tid < 64) {
            const float g2c = g2v, g3c = g3v, g4c = g4v;
            g2v = G2[(b * L + t + 1) * 64 + l];      // prefetch next step
            g3v = G3[(b * L + t + 1) * 64 + l];
            g4v = G4it[(b * L + t + 1) * 64 + l];

            float htd = 0.f;                         // fold h_tilde_t
            #pragma unroll
            for (int ww = 0; ww < 8; ++ww) htd += red[ww * 64 + l];
            htS[l] = htd;
            htH[t * 64 + l] = htd;

            float g2 = g2c, g3 = g3c;                // 64-dots from LDS
            #pragma unroll
            for (int k4 = 0; k4 < 16; ++k4) {
                const f32x4 h4 = *(const f32x4*)&htS[k4 * 4];
                #pragma unroll
                for (int j = 0; j < 4; ++j) {
                    const float2 wv = w23S[(k4 * 4 + j) * 64 + l];
                    g2 += wv.x * h4[j];
                    g3 += wv.y * h4[j];
                }
            }
            const float lg = sigm(g3) * (tanhf(g2) + 1.0f) * 0.5f;
            LGs[l] = lg;
            float v = g4c;
            #pragma unroll
            for (int k4 = 0; k4 < 16; ++k4) {
                const f32x4 lg4 = *(const f32x4*)&LGs[k4 * 4];
                #pragma unroll
                for (int j = 0; j < 4; ++j) v += w4bS[(k4 * 4 + j) * 64 + l] * lg4[j];
            }
            Vs[l] = v;
        }
        __syncthreads();                             // barrier B: LGs/Vs ready

        // MFMA + epilogue (round-9 verified math)
        f32x4 part[4];
        #pragma unroll
        for (int dt = 0; dt < 4; ++dt) part[dt] = f32x4{0.f, 0.f, 0.f, 0.f};

        #pragma unroll
        for (int half = 0; half < 2; ++half) {
            f32x4 acc[2][4];
            #pragma unroll
            for (int d2 = 0; d2 < 2; ++d2)
                #pragma unroll
                for (int st = 0; st < 4; ++st) acc[d2][st] = f32x4{0.f, 0.f, 0.f, 0.f};

            #pragma unroll
            for (int d2 = 0; d2 < 2; ++d2) {
                const int dt = half * 2 + d2;
                #pragma unroll
                for (int st = 0; st < 4; ++st) {
                    acc[d2][st] = __builtin_amdgcn_mfma_f32_16x16x32_bf16(
                        afr[dt][0], bfr[st][0], acc[d2][st], 0, 0, 0);
                    acc[d2][st] = __builtin_amdgcn_mfma_f32_16x16x32_bf16(
                        afr[dt][1], bfr[st][1], acc[d2][st], 0, 0, 0);
                }
            }

            #pragma unroll
            for (int d2 = 0; d2 < 2; ++d2) {
                const int dt = half * 2 + d2;
                const int d0 = dt * 16 + lk * 4;
                const f32x4 lg4 = *(const f32x4*)&LGs[d0];
                const f32x4 v4  = *(const f32x4*)&Vs[d0];
                #pragma unroll
                for (int st = 0; st < 4; ++st) {
                    const int s = (w * 4 + st) * 16 + lm;
                    const float qe = qQ[cur][s];
                    const float qq = qQ[nxt][s];
                    const f32x4 a  = acc[d2][st];
                    const f32x4 ho = hreg[st][dt];
                    f32x4 hn;
                    hn.x = qe * lg4.x + sigm(a.x + v4.x) * ho.x;
                    hn.y = qe * lg4.y + sigm(a.y + v4.y) * ho.y;
                    hn.z = qe * lg4.z + sigm(a.z + v4.z) * ho.z;
                    hn.w = qe * lg4.w + sigm(a.w + v4.w) * ho.w;
                    hreg[st][dt] = hn;
                    const u32 lo = (u32)f2bf(hn.x) | ((u32)f2bf(hn.y) << 16);
                    const u32 hi = (u32)f2bf(hn.z) | ((u32)f2bf(hn.w) << 16);
                    *(uint2*)&hB[s * 72 + d0] = make_uint2(lo, hi);
                    part[dt] += qq * hn;
                }
            }
        }

        // h_tilde_{t+1} partials: shfl over 16 s-lanes, write red
        #pragma unroll
        for (int dt = 0; dt < 4; ++dt)
            #pragma unroll
            for (int i = 0; i < 4; ++i) {
                float v = part[dt][i];
                v += __shfl_xor(v, 1); v += __shfl_xor(v, 2);
                v += __shfl_xor(v, 4); v += __shfl_xor(v, 8);
                part[dt][i] = v;
            }
        if (lm == 0) {
            #pragma unroll
            for (int dt = 0; dt < 4; ++dt)
                *(f32x4*)&red[w * 64 + dt * 16 + lk * 4] = part[dt];
        }
        __syncthreads();                             // barrier A: red ready
    }

    // final fold: h_tilde_99 -> htH[99]
    if (tid < 64) {
        float htd = 0.f;
        #pragma unroll
        for (int ww = 0; ww < 8; ++ww) htd += red[ww * 64 + l];
        htH[99 * 64 + l] = htd;
    }
    __syncthreads();
    // bulk write history to global (coalesced)
    for (int i = tid; i < 100 * 64; i += 512)
        hthist[(size_t)(i >> 6) * (B * 64) + b * 64 + (i & 63)] = htH[i];
}

// ---------------- epilogue: y_t for t=1..99 --------------------------------
__global__ __launch_bounds__(64) void k_y(
    const float* __restrict__ hthist, const float* __restrict__ prey,
    const float* __restrict__ W5T, float* __restrict__ pred)
{
    __shared__ float HT[64];
    const int j = blockIdx.x + 1;    // 1..99
    const int b = blockIdx.y;
    const int d = threadIdx.x;
    HT[d] = hthist[(size_t)j * (B * 64) + b * 64 + d];
    __syncthreads();
    float acc = prey[(b * L + j) * 64 + d];
    #pragma unroll 8
    for (int k = 0; k < 64; ++k) acc += W5T[(128 + k) * 64 + d] * HT[k];
    float y = sigm(acc);
    #pragma unroll
    for (int m = 1; m < 64; m <<= 1) y += __shfl_xor(y, m);
    if (d == 0) pred[b * L + j] = y * (1.0f / 64.0f);
}

} // namespace

extern "C" void kernel_launch(void* const* d_in, const int* in_sizes, int n_in,
                              void* d_out, int out_size, void* d_ws, size_t ws_size,
                              hipStream_t stream)
{
    const int*   e_data   = (const int*)d_in[0];
    const int*   a_data   = (const int*)d_in[1];
    const int*   at_data  = (const int*)d_in[2];
    const int*   it_data  = (const int*)d_in[3];
    const float* q_matrix = (const float*)d_in[4];
    const float* h0       = (const float*)d_in[5];
    const float* e_embed  = (const float*)d_in[6];
    const float* at_embed = (const float*)d_in[7];
    const float* it_embed = (const float*)d_in[8];
    const float* W1 = (const float*)d_in[9];  const float* b1 = (const float*)d_in[10];
    const float* W2 = (const float*)d_in[11]; const float* b2 = (const float*)d_in[12];
    const float* W3 = (const float*)d_in[13]; const float* b3 = (const float*)d_in[14];
    const float* W4 = (const float*)d_in[15]; const float* b4 = (const float*)d_in[16];
    const float* W5 = (const float*)d_in[17]; const float* b5 = (const float*)d_in[18];
    float* pred = (float*)d_out;

    float* ws   = (float*)d_ws;
    float* W1T    = ws;                        // 16384
    float* W2T    = W1T    + 16384;            // 16384
    float* W3T    = W2T    + 16384;            // 16384
    float* W4T    = W3T    + 16384;            // 12288
    float* W5T    = W4T    + 12288;            // 12288
    float* allL   = W5T    + 12288;            // 204800
    float* G2     = allL   + 204800;
    float* G3     = G2     + 204800;
    float* G4it   = G3     + 204800;
    float* prey   = G4it   + 204800;
    float* hthist = prey   + 204800;           // L*B*64 = 204800
    // total ~5.2 MB

    hipLaunchKernelGGL(k_init, dim3(64), dim3(256), 0, stream,
                       W1, W2, W3, W4, W5, W1T, W2T, W3T, W4T, W5T, pred);
    hipLaunchKernelGGL(k_all_learning, dim3(B * L / 4), dim3(256), 0, stream,
                       e_data, a_data, at_data, e_embed, at_embed, W1T, b1, allL);
    hipLaunchKernelGGL(k_pre, dim3(B * L / 4), dim3(256), 0, stream,
                       e_data, it_data, e_embed, it_embed, allL,
                       W2T, W3T, W4T, W5T, b2, b3, b4, b5, G2, G3, G4it, prey);
    hipLaunchKernelGGL(k_steps, dim3(B), dim3(512), 0, stream,
                       G2, G3, G4it, W2T, W3T, W4T, W4,
                       q_matrix, e_data, h0, hthist);
    hipLaunchKernelGGL(k_y, dim3(L - 1, B), dim3(64), 0, stream,
                       hthist, prey, W5T, pred);
}

// Round 12
// 755.128 us; speedup vs baseline: 1.8011x; 1.8011x over previous
//
#include <hip/hip_runtime.h>
#include <hip/hip_bf16.h>

namespace {

constexpr int B  = 32;
constexpr int L  = 100;
constexpr int S  = 501;
constexpr int DK = 64;
constexpr int DE = 128;

typedef __attribute__((ext_vector_type(8))) short short8v;   // 8 bf16 (4 VGPR)
typedef __attribute__((ext_vector_type(4))) float f32x4;
typedef unsigned int u32;

__device__ __forceinline__ float sigm(float x) {
    return __fdividef(1.0f, 1.0f + __expf(-x));
}
// fp32 -> bf16 RNE
__device__ __forceinline__ unsigned short f2bf(float f) {
    u32 u = __float_as_uint(f);
    u += 0x7FFFu + ((u >> 16) & 1u);
    return (unsigned short)(u >> 16);
}
// pack two fp32 -> u32 of 2 bf16 (RNE)
__device__ __forceinline__ u32 pack2(float a, float b) {
    return (u32)f2bf(a) | ((u32)f2bf(b) << 16);
}

// ---------------- init: transpose weights (k-major) for pre/y, pred[:,0] ---
__global__ __launch_bounds__(256) void k_init(
    const float* __restrict__ W1, const float* __restrict__ W2,
    const float* __restrict__ W3, const float* __restrict__ W4,
    const float* __restrict__ W5,
    float* __restrict__ W1T, float* __restrict__ W2T, float* __restrict__ W3T,
    float* __restrict__ W4T, float* __restrict__ W5T,
    float* __restrict__ pred)
{
    const int idx = blockIdx.x * 256 + threadIdx.x;
    const int st  = gridDim.x * 256;
    for (int i = idx; i < 64 * 256; i += st) {
        int dd = i >> 8, kk = i & 255;
        W1T[kk * 64 + dd] = W1[i];
        W2T[kk * 64 + dd] = W2[i];
        W3T[kk * 64 + dd] = W3[i];
    }
    for (int i = idx; i < 64 * 192; i += st) {
        int dd = i / 192, kk = i % 192;
        W4T[kk * 64 + dd] = W4[i];
        W5T[kk * 64 + dd] = W5[i];
    }
    if (idx < B) pred[idx * L] = 0.0f;
}

// ---------------- all_learning = concat(e,at,a) @ W1^T + b1 ----------------
__global__ __launch_bounds__(256) void k_all_learning(
    const int* __restrict__ e_data, const int* __restrict__ a_data,
    const int* __restrict__ at_data,
    const float* __restrict__ e_embed, const float* __restrict__ at_embed,
    const float* __restrict__ W1T, const float* __restrict__ b1,
    float* __restrict__ allL)
{
    __shared__ float in_s[4][257];
    const int g = threadIdx.x >> 6;
    const int d = threadIdx.x & 63;
    const int row = blockIdx.x * 4 + g;
    const int e  = e_data[row];
    const int at = at_data[row];
    in_s[g][d]       = e_embed[(size_t)e * DE + d];
    in_s[g][64 + d]  = e_embed[(size_t)e * DE + 64 + d];
    in_s[g][128 + d] = at_embed[(size_t)at * DK + d];
    in_s[g][192 + d] = (float)a_data[row];
    __syncthreads();
    float acc = b1[d];
    #pragma unroll 8
    for (int k = 0; k < 256; ++k) acc += W1T[k * 64 + d] * in_s[g][k];
    allL[row * DK + d] = acc;
}

// ---------------- G2,G3 (non-recurrent parts), G4it, prey ------------------
__global__ __launch_bounds__(256) void k_pre(
    const int* __restrict__ e_data, const int* __restrict__ it_data,
    const float* __restrict__ e_embed, const float* __restrict__ it_embed,
    const float* __restrict__ allL,
    const float* __restrict__ W2T, const float* __restrict__ W3T,
    const float* __restrict__ W4T, const float* __restrict__ W5T,
    const float* __restrict__ b2, const float* __restrict__ b3,
    const float* __restrict__ b4, const float* __restrict__ b5,
    float* __restrict__ G2, float* __restrict__ G3,
    float* __restrict__ G4it, float* __restrict__ prey)
{
    __shared__ float lp[4][64], its[4][64], ln[4][64], ee[4][128];
    const int g = threadIdx.x >> 6;
    const int d = threadIdx.x & 63;
    const int row = blockIdx.x * 4 + g;
    const int t = row % L;
    lp[g][d]  = (t == 0) ? 0.0f : allL[(row - 1) * 64 + d];
    its[g][d] = it_embed[(size_t)it_data[row] * 64 + d];
    ln[g][d]  = allL[row * 64 + d];
    const int e = e_data[row];
    ee[g][d]      = e_embed[(size_t)e * DE + d];
    ee[g][64 + d] = e_embed[(size_t)e * DE + 64 + d];
    __syncthreads();
    float g2 = b2[d], g3 = b3[d], g4 = b4[d], py = b5[d];
    #pragma unroll 4
    for (int k = 0; k < 64; ++k) {
        const float l0 = lp[g][k], i0 = its[g][k], n0 = ln[g][k];
        g2 += W2T[k * 64 + d] * l0 + W2T[(64 + k) * 64 + d] * i0 + W2T[(128 + k) * 64 + d] * n0;
        g3 += W3T[k * 64 + d] * l0 + W3T[(64 + k) * 64 + d] * i0 + W3T[(128 + k) * 64 + d] * n0;
        g4 += W4T[(128 + k) * 64 + d] * i0;
        py += W5T[k * 64 + d] * ee[g][k] + W5T[(64 + k) * 64 + d] * ee[g][64 + k];
    }
    G2[row * 64 + d]   = g2;
    G3[row * 64 + d]   = g3;
    G4it[row * 64 + d] = g4;
    prey[row * 64 + d] = py;
}

// ---------------- persistent recurrence: one block per BATCH ---------------
// 32 blocks x 512 threads (8 waves). Round-9 parallel phasing (6 barriers)
// with: 2-round shfl reduce (red4 32x64), q row + G2/G3/G4 register prefetch
// one step ahead, q stored as float2 {qe,qn}, h_tilde history in LDS (bulk
// write at end).
__global__ __launch_bounds__(512, 1) void k_steps(
    const float* __restrict__ G2, const float* __restrict__ G3,
    const float* __restrict__ G4it,
    const float* __restrict__ W2, const float* __restrict__ W3,
    const float* __restrict__ W4,
    const float* __restrict__ q_matrix, const int* __restrict__ e_data,
    const float* __restrict__ h0, float* __restrict__ hthist)
{
    __shared__ unsigned short hB[512 * 72];   // h mirror bf16 (73728 B)
    __shared__ float2 qP[512];                // {q[e_t], q[e_{t+1}]} (4096 B)
    __shared__ float htH[100 * 64];           // h_tilde history (25600 B)
    __shared__ float htS[64], LGs[64], Vs[64];
    __shared__ float red[512], red2[512];     // gate-dot partials (4096 B)
    __shared__ float red4[32 * 64];           // h_tilde partials  (8192 B)
    __shared__ int eRow[104];                 // ~117 KB total

    const int tid = threadIdx.x;
    const int b   = blockIdx.x;
    const int l   = tid & 63;     // lane
    const int w   = tid >> 6;     // wave 0..7
    const int lm  = l & 15;
    const int lk  = l >> 4;
    const int d   = tid & 63;     // gate-phase d index
    const int kg  = tid >> 6;     // gate-phase k group 0..7

    // ---- per-thread gate weight registers ----
    float w2r[8], w3r[8], wbr[8];
    #pragma unroll
    for (int j = 0; j < 8; ++j) {
        w2r[j] = W2[d * 256 + 192 + kg * 8 + j];
        w3r[j] = W3[d * 256 + 192 + kg * 8 + j];
        wbr[j] = W4[d * 192 + 64  + kg * 8 + j];
    }

    // ---- A-fragments: W4a[d][k] bf16, persistent in regs ----
    short8v afr[4][2];
    #pragma unroll
    for (int dt = 0; dt < 4; ++dt)
        #pragma unroll
        for (int kc = 0; kc < 2; ++kc) {
            const float* src = W4 + (size_t)(dt * 16 + lm) * 192 + kc * 32 + lk * 8;
            union { unsigned short us[8]; short8v v; } u;
            #pragma unroll
            for (int j = 0; j < 8; ++j) u.us[j] = f2bf(src[j]);
            afr[dt][kc] = u.v;
        }

    if (tid < L) eRow[tid] = e_data[b * L + tid];

    // ---- h registers + bf16 LDS mirror ----
    f32x4 hreg[4][4];   // [st][dt]: h[s][d0..3], s=(w*4+st)*16+lm, d0=dt*16+lk*4
    #pragma unroll
    for (int st = 0; st < 4; ++st) {
        const int s = (w * 4 + st) * 16 + lm;
        #pragma unroll
        for (int dt = 0; dt < 4; ++dt) {
            const int d0 = dt * 16 + lk * 4;
            f32x4 hv = {0.f, 0.f, 0.f, 0.f};
            if (s < S) hv = *(const f32x4*)(h0 + (size_t)s * 64 + d0);
            hreg[st][dt] = hv;
            *(uint2*)&hB[s * 72 + d0] =
                make_uint2(pack2(hv.x, hv.y), pack2(hv.z, hv.w));
        }
    }
    __syncthreads();                               // eRow/hB ready

    // ---- prologue: qP = {q[e0], q[e1]}; prefetch G[t=0] ----
    {
        const float q0 = (tid < S) ? q_matrix[(size_t)eRow[0] * S + tid] : 0.f;
        const float q1 = (tid < S) ? q_matrix[(size_t)eRow[1] * S + tid] : 0.f;
        qP[tid] = make_float2(q0, q1);
    }
    float g2v = 0.f, g3v = 0.f, g4v = 0.f;
    if (tid < 64) {
        g2v = G2[(b * L) * 64 + l];
        g3v = G3[(b * L) * 64 + l];
        g4v = G4it[(b * L) * 64 + l];
    }
    __syncthreads();                               // qP ready

    // ---- h_tilde_0 partials (2-round shfl -> red4) ----
    {
        f32x4 part[4];
        #pragma unroll
        for (int dt = 0; dt < 4; ++dt) part[dt] = f32x4{0.f, 0.f, 0.f, 0.f};
        #pragma unroll
        for (int st = 0; st < 4; ++st) {
            const int s = (w * 4 + st) * 16 + lm;
            const float qe = qP[s].x;
            #pragma unroll
            for (int dt = 0; dt < 4; ++dt) part[dt] += qe * hreg[st][dt];
        }
        #pragma unroll
        for (int dt = 0; dt < 4; ++dt)
            #pragma unroll
            for (int i = 0; i < 4; ++i) {
                float v = part[dt][i];
                v += __shfl_xor(v, 1); v += __shfl_xor(v, 2);
                part[dt][i] = v;
            }
        if ((lm & 3) == 0) {
            const int g = w * 4 + (lm >> 2);
            #pragma unroll
            for (int dt = 0; dt < 4; ++dt)
                *(f32x4*)&red4[g * 64 + dt * 16 + lk * 4] = part[dt];
        }
    }
    __syncthreads();
    if (tid < 64) {
        float htd = 0.f;
        #pragma unroll
        for (int g = 0; g < 32; ++g) htd += red4[g * 64 + l];
        htS[l] = htd;
        htH[l] = htd;
    }
    __syncthreads();

    float qn_reg = 0.f;   // holds q[e_{t+2}] row element (loaded in-loop)

    // ---------------- 99 steps ----------------
    for (int t = 0; t < L - 1; ++t) {
        // P1 (all waves): shift qP, issue next q load, bfr reads, gate partials
        if (t > 0) {
            const float2 qold = qP[tid];
            qP[tid] = make_float2(qold.y, qn_reg);
        }
        {
            const int tn = (t + 2 < L) ? t + 2 : L - 1;
            qn_reg = (tid < S) ? q_matrix[(size_t)eRow[tn] * S + tid] : 0.f;
        }
        short8v bfr[4][2];
        #pragma unroll
        for (int st = 0; st < 4; ++st) {
            const int s = (w * 4 + st) * 16 + lm;
            #pragma unroll
            for (int kc = 0; kc < 2; ++kc)
                bfr[st][kc] = *(const short8v*)&hB[s * 72 + kc * 32 + lk * 8];
        }
        {
            const f32x4 h4a = *(const f32x4*)&htS[kg * 8];
            const f32x4 h4b = *(const f32x4*)&htS[kg * 8 + 4];
            float p2 = 0.f, p3 = 0.f;
            #pragma unroll
            for (int j = 0; j < 4; ++j) {
                p2 += w2r[j] * h4a[j] + w2r[4 + j] * h4b[j];
                p3 += w3r[j] * h4a[j] + w3r[4 + j] * h4b[j];
            }
            red[kg * 64 + d]  = p2;
            red2[kg * 64 + d] = p3;
        }
        __syncthreads();                           // b1

        // P2 (wave 0): LG
        if (tid < 64) {
            float g2 = g2v, g3 = g3v;
            #pragma unroll
            for (int ww = 0; ww < 8; ++ww) { g2 += red[ww * 64 + d]; g3 += red2[ww * 64 + d]; }
            LGs[d] = sigm(g3) * (tanhf(g2) + 1.0f) * 0.5f;
        }
        __syncthreads();                           // b2

        // P3 (all waves): W4b @ LG partials
        {
            const f32x4 l4a = *(const f32x4*)&LGs[kg * 8];
            const f32x4 l4b = *(const f32x4*)&LGs[kg * 8 + 4];
            float pv = 0.f;
            #pragma unroll
            for (int j = 0; j < 4; ++j)
                pv += wbr[j] * l4a[j] + wbr[4 + j] * l4b[j];
            red[kg * 64 + d] = pv;
        }
        __syncthreads();                           // b3

        // P4 (wave 0): Vs fold + G prefetch for next step
        if (tid < 64) {
            float v = g4v;
            #pragma unroll
            for (int ww = 0; ww < 8; ++ww) v += red[ww * 64 + d];
            Vs[d] = v;
            g2v = G2[(b * L + t + 1) * 64 + l];
            g3v = G3[(b * L + t + 1) * 64 + l];
            g4v = G4it[(b * L + t + 1) * 64 + l];
        }
        __syncthreads();                           // b4

        // P5: MFMA + epilogue
        float2 qv[4];
        #pragma unroll
        for (int st = 0; st < 4; ++st) qv[st] = qP[(w * 4 + st) * 16 + lm];

        f32x4 part[4];
        #pragma unroll
        for (int dt = 0; dt < 4; ++dt) part[dt] = f32x4{0.f, 0.f, 0.f, 0.f};

        #pragma unroll
        for (int half = 0; half < 2; ++half) {
            f32x4 acc[2][4];
            #pragma unroll
            for (int d2 = 0; d2 < 2; ++d2)
                #pragma unroll
                for (int st = 0; st < 4; ++st) acc[d2][st] = f32x4{0.f, 0.f, 0.f, 0.f};

            #pragma unroll
            for (int d2 = 0; d2 < 2; ++d2) {
                const int dt = half * 2 + d2;
                #pragma unroll
                for (int st = 0; st < 4; ++st) {
                    acc[d2][st] = __builtin_amdgcn_mfma_f32_16x16x32_bf16(
                        afr[dt][0], bfr[st][0], acc[d2][st], 0, 0, 0);
                    acc[d2][st] = __builtin_amdgcn_mfma_f32_16x16x32_bf16(
                        afr[dt][1], bfr[st][1], acc[d2][st], 0, 0, 0);
                }
            }

            #pragma unroll
            for (int d2 = 0; d2 < 2; ++d2) {
                const int dt = half * 2 + d2;
                const int d0 = dt * 16 + lk * 4;
                const f32x4 lg4 = *(const f32x4*)&LGs[d0];
                const f32x4 v4  = *(const f32x4*)&Vs[d0];
                #pragma unroll
                for (int st = 0; st < 4; ++st) {
                    const int s = (w * 4 + st) * 16 + lm;
                    const float qe = qv[st].x;
                    const float qq = qv[st].y;
                    const f32x4 a  = acc[d2][st];
                    const f32x4 ho = hreg[st][dt];
                    f32x4 hn;
                    hn.x = qe * lg4.x + sigm(a.x + v4.x) * ho.x;
                    hn.y = qe * lg4.y + sigm(a.y + v4.y) * ho.y;
                    hn.z = qe * lg4.z + sigm(a.z + v4.z) * ho.z;
                    hn.w = qe * lg4.w + sigm(a.w + v4.w) * ho.w;
                    hreg[st][dt] = hn;
                    *(uint2*)&hB[s * 72 + d0] =
                        make_uint2(pack2(hn.x, hn.y), pack2(hn.z, hn.w));
                    part[dt] += qq * hn;
                }
            }
        }

        // h_tilde_{t+1} partials: 2-round shfl, 16 writer lanes -> red4
        #pragma unroll
        for (int dt = 0; dt < 4; ++dt)
            #pragma unroll
            for (int i = 0; i < 4; ++i) {
                float v = part[dt][i];
                v += __shfl_xor(v, 1); v += __shfl_xor(v, 2);
                part[dt][i] = v;
            }
        if ((lm & 3) == 0) {
            const int g = w * 4 + (lm >> 2);
            #pragma unroll
            for (int dt = 0; dt < 4; ++dt)
                *(f32x4*)&red4[g * 64 + dt * 16 + lk * 4] = part[dt];
        }
        __syncthreads();                           // b5

        // P6 (wave 0): fold h_tilde_{t+1} -> htS, htH
        if (tid < 64) {
            float htd = 0.f;
            #pragma unroll
            for (int g = 0; g < 32; ++g) htd += red4[g * 64 + l];
            htS[l] = htd;
            htH[(t + 1) * 64 + l] = htd;
        }
        __syncthreads();                           // b6
    }

    // bulk write h_tilde history to global (coalesced)
    for (int i = tid; i < 100 * 64; i += 512)
        hthist[(size_t)(i >> 6) * (B * 64) + b * 64 + (i & 63)] = htH[i];
}

// ---------------- epilogue: y_t for t=1..99 --------------------------------
__global__ __launch_bounds__(64) void k_y(
    const float* __restrict__ hthist, const float* __restrict__ prey,
    const float* __restrict__ W5T, float* __restrict__ pred)
{
    __shared__ float HT[64];
    const int j = blockIdx.x + 1;    // 1..99
    const int b = blockIdx.y;
    const int d = threadIdx.x;
    HT[d] = hthist[(size_t)j * (B * 64) + b * 64 + d];
    __syncthreads();
    float acc = prey[(b * L + j) * 64 + d];
    #pragma unroll 8
    for (int k = 0; k < 64; ++k) acc += W5T[(128 + k) * 64 + d] * HT[k];
    float y = sigm(acc);
    #pragma unroll
    for (int m = 1; m < 64; m <<= 1) y += __shfl_xor(y, m);
    if (d == 0) pred[b * L + j] = y * (1.0f / 64.0f);
}

} // namespace

extern "C" void kernel_launch(void* const* d_in, const int* in_sizes, int n_in,
                              void* d_out, int out_size, void* d_ws, size_t ws_size,
                              hipStream_t stream)
{
    const int*   e_data   = (const int*)d_in[0];
    const int*   a_data   = (const int*)d_in[1];
    const int*   at_data  = (const int*)d_in[2];
    const int*   it_data  = (const int*)d_in[3];
    const float* q_matrix = (const float*)d_in[4];
    const float* h0       = (const float*)d_in[5];
    const float* e_embed  = (const float*)d_in[6];
    const float* at_embed = (const float*)d_in[7];
    const float* it_embed = (const float*)d_in[8];
    const float* W1 = (const float*)d_in[9];  const float* b1 = (const float*)d_in[10];
    const float* W2 = (const float*)d_in[11]; const float* b2 = (const float*)d_in[12];
    const float* W3 = (const float*)d_in[13]; const float* b3 = (const float*)d_in[14];
    const float* W4 = (const float*)d_in[15]; const float* b4 = (const float*)d_in[16];
    const float* W5 = (const float*)d_in[17]; const float* b5 = (const float*)d_in[18];
    float* pred = (float*)d_out;

    float* ws   = (float*)d_ws;
    float* W1T    = ws;                        // 16384
    float* W2T    = W1T    + 16384;            // 16384
    float* W3T    = W2T    + 16384;            // 16384
    float* W4T    = W3T    + 16384;            // 12288
    float* W5T    = W4T    + 12288;            // 12288
    float* allL   = W5T    + 12288;            // 204800
    float* G2     = allL   + 204800;
    float* G3     = G2     + 204800;
    float* G4it   = G3     + 204800;
    float* prey   = G4it   + 204800;
    float* hthist = prey   + 204800;           // L*B*64 = 204800
    // total ~5.2 MB

    hipLaunchKernelGGL(k_init, dim3(64), dim3(256), 0, stream,
                       W1, W2, W3, W4, W5, W1T, W2T, W3T, W4T, W5T, pred);
    hipLaunchKernelGGL(k_all_learning, dim3(B * L / 4), dim3(256), 0, stream,
                       e_data, a_data, at_data, e_embed, at_embed, W1T, b1, allL);
    hipLaunchKernelGGL(k_pre, dim3(B * L / 4), dim3(256), 0, stream,
                       e_data, it_data, e_embed, it_embed, allL,
                       W2T, W3T, W4T, W5T, b2, b3, b4, b5, G2, G3, G4it, prey);
    hipLaunchKernelGGL(k_steps, dim3(B), dim3(512), 0, stream,
                       G2, G3, G4it, W2, W3, W4, q_matrix, e_data, h0, hthist);
    hipLaunchKernelGGL(k_y, dim3(L - 1, B), dim3(64), 0, stream,
                       hthist, prey, W5T, pred);
}

// Round 13
// 724.819 us; speedup vs baseline: 1.8764x; 1.0418x over previous
//
#include <hip/hip_runtime.h>
#include <hip/hip_bf16.h>

namespace {

constexpr int B  = 32;
constexpr int L  = 100;
constexpr int S  = 501;
constexpr int DK = 64;
constexpr int DE = 128;

typedef __attribute__((ext_vector_type(8))) short short8v;   // 8 bf16 (4 VGPR)
typedef __attribute__((ext_vector_type(4))) float f32x4;
typedef unsigned int u32;

__device__ __forceinline__ float sigm(float x) {
    return __fdividef(1.0f, 1.0f + __expf(-x));
}
// fp32 -> bf16 RNE (one-time staging only)
__device__ __forceinline__ unsigned short f2bf(float f) {
    u32 u = __float_as_uint(f);
    u += 0x7FFFu + ((u >> 16) & 1u);
    return (unsigned short)(u >> 16);
}
// pack two fp32 -> u32 of 2 bf16, round-half-up (4 ops; hot path)
__device__ __forceinline__ u32 pack2(float a, float b) {
    const u32 ua = __float_as_uint(a) + 0x8000u;
    const u32 ub = __float_as_uint(b) + 0x8000u;
    return (ua >> 16) | (ub & 0xFFFF0000u);
}

// ---------------- init: transpose weights (k-major) for pre/y, pred[:,0] ---
__global__ __launch_bounds__(256) void k_init(
    const float* __restrict__ W1, const float* __restrict__ W2,
    const float* __restrict__ W3, const float* __restrict__ W4,
    const float* __restrict__ W5,
    float* __restrict__ W1T, float* __restrict__ W2T, float* __restrict__ W3T,
    float* __restrict__ W4T, float* __restrict__ W5T,
    float* __restrict__ pred)
{
    const int idx = blockIdx.x * 256 + threadIdx.x;
    const int st  = gridDim.x * 256;
    for (int i = idx; i < 64 * 256; i += st) {
        int dd = i >> 8, kk = i & 255;
        W1T[kk * 64 + dd] = W1[i];
        W2T[kk * 64 + dd] = W2[i];
        W3T[kk * 64 + dd] = W3[i];
    }
    for (int i = idx; i < 64 * 192; i += st) {
        int dd = i / 192, kk = i % 192;
        W4T[kk * 64 + dd] = W4[i];
        W5T[kk * 64 + dd] = W5[i];
    }
    if (idx < B) pred[idx * L] = 0.0f;
}

// ---------------- all_learning = concat(e,at,a) @ W1^T + b1 ----------------
__global__ __launch_bounds__(256) void k_all_learning(
    const int* __restrict__ e_data, const int* __restrict__ a_data,
    const int* __restrict__ at_data,
    const float* __restrict__ e_embed, const float* __restrict__ at_embed,
    const float* __restrict__ W1T, const float* __restrict__ b1,
    float* __restrict__ allL)
{
    __shared__ float in_s[4][257];
    const int g = threadIdx.x >> 6;
    const int d = threadIdx.x & 63;
    const int row = blockIdx.x * 4 + g;
    const int e  = e_data[row];
    const int at = at_data[row];
    in_s[g][d]       = e_embed[(size_t)e * DE + d];
    in_s[g][64 + d]  = e_embed[(size_t)e * DE + 64 + d];
    in_s[g][128 + d] = at_embed[(size_t)at * DK + d];
    in_s[g][192 + d] = (float)a_data[row];
    __syncthreads();
    float acc = b1[d];
    #pragma unroll 8
    for (int k = 0; k < 256; ++k) acc += W1T[k * 64 + d] * in_s[g][k];
    allL[row * DK + d] = acc;
}

// ---------------- G2,G3 (non-recurrent parts), G4it, prey ------------------
__global__ __launch_bounds__(256) void k_pre(
    const int* __restrict__ e_data, const int* __restrict__ it_data,
    const float* __restrict__ e_embed, const float* __restrict__ it_embed,
    const float* __restrict__ allL,
    const float* __restrict__ W2T, const float* __restrict__ W3T,
    const float* __restrict__ W4T, const float* __restrict__ W5T,
    const float* __restrict__ b2, const float* __restrict__ b3,
    const float* __restrict__ b4, const float* __restrict__ b5,
    float* __restrict__ G2, float* __restrict__ G3,
    float* __restrict__ G4it, float* __restrict__ prey)
{
    __shared__ float lp[4][64], its[4][64], ln[4][64], ee[4][128];
    const int g = threadIdx.x >> 6;
    const int d = threadIdx.x & 63;
    const int row = blockIdx.x * 4 + g;
    const int t = row % L;
    lp[g][d]  = (t == 0) ? 0.0f : allL[(row - 1) * 64 + d];
    its[g][d] = it_embed[(size_t)it_data[row] * 64 + d];
    ln[g][d]  = allL[row * 64 + d];
    const int e = e_data[row];
    ee[g][d]      = e_embed[(size_t)e * DE + d];
    ee[g][64 + d] = e_embed[(size_t)e * DE + 64 + d];
    __syncthreads();
    float g2 = b2[d], g3 = b3[d], g4 = b4[d], py = b5[d];
    #pragma unroll 4
    for (int k = 0; k < 64; ++k) {
        const float l0 = lp[g][k], i0 = its[g][k], n0 = ln[g][k];
        g2 += W2T[k * 64 + d] * l0 + W2T[(64 + k) * 64 + d] * i0 + W2T[(128 + k) * 64 + d] * n0;
        g3 += W3T[k * 64 + d] * l0 + W3T[(64 + k) * 64 + d] * i0 + W3T[(128 + k) * 64 + d] * n0;
        g4 += W4T[(128 + k) * 64 + d] * i0;
        py += W5T[k * 64 + d] * ee[g][k] + W5T[(64 + k) * 64 + d] * ee[g][64 + k];
    }
    G2[row * 64 + d]   = g2;
    G3[row * 64 + d]   = g3;
    G4it[row * 64 + d] = g4;
    prey[row * 64 + d] = py;
}

// ---------------- persistent recurrence: one block per BATCH ---------------
// 32 blocks x 512 threads (8 waves). Parallel phasing, 6 barriers/step.
// NEW vs r12: (1) MFMA software-pipelined one phase ahead — bfr reads + 32
// MFMAs issue right after the epilogue's wave-private hB writes, acc[4][4]
// carried across the gate phases; (2) red4 rows padded to 68 dwords (kills
// the 4-way write conflict, 68 % 32 = 4); (3) pack2 = round-half-up, 4 ops.
__global__ __launch_bounds__(512, 1) void k_steps(
    const float* __restrict__ G2, const float* __restrict__ G3,
    const float* __restrict__ G4it,
    const float* __restrict__ W2, const float* __restrict__ W3,
    const float* __restrict__ W4,
    const float* __restrict__ q_matrix, const int* __restrict__ e_data,
    const float* __restrict__ h0, float* __restrict__ hthist)
{
    __shared__ unsigned short hB[512 * 72];   // h mirror bf16 (73728 B)
    __shared__ float2 qP[512];                // {q[e_t], q[e_{t+1}]} (4096 B)
    __shared__ float htH[100 * 64];           // h_tilde history (25600 B)
    __shared__ float htS[64], LGs[64], Vs[64];
    __shared__ float red[512], red2[512];     // gate-dot partials (4096 B)
    __shared__ float red4[32 * 68];           // h_tilde partials, padded (8704 B)
    __shared__ int eRow[104];                 // ~118 KB total

    const int tid = threadIdx.x;
    const int b   = blockIdx.x;
    const int l   = tid & 63;     // lane
    const int w   = tid >> 6;     // wave 0..7
    const int lm  = l & 15;
    const int lk  = l >> 4;
    const int d   = tid & 63;     // gate-phase d index
    const int kg  = tid >> 6;     // gate-phase k group 0..7

    // ---- per-thread gate weight registers ----
    float w2r[8], w3r[8], wbr[8];
    #pragma unroll
    for (int j = 0; j < 8; ++j) {
        w2r[j] = W2[d * 256 + 192 + kg * 8 + j];
        w3r[j] = W3[d * 256 + 192 + kg * 8 + j];
        wbr[j] = W4[d * 192 + 64  + kg * 8 + j];
    }

    // ---- A-fragments: W4a[d][k] bf16, persistent in regs ----
    short8v afr[4][2];
    #pragma unroll
    for (int dt = 0; dt < 4; ++dt)
        #pragma unroll
        for (int kc = 0; kc < 2; ++kc) {
            const float* src = W4 + (size_t)(dt * 16 + lm) * 192 + kc * 32 + lk * 8;
            union { unsigned short us[8]; short8v v; } u;
            #pragma unroll
            for (int j = 0; j < 8; ++j) u.us[j] = f2bf(src[j]);
            afr[dt][kc] = u.v;
        }

    if (tid < L) eRow[tid] = e_data[b * L + tid];

    // ---- h registers + bf16 LDS mirror ----
    f32x4 hreg[4][4];   // [st][dt]: h[s][d0..3], s=(w*4+st)*16+lm, d0=dt*16+lk*4
    #pragma unroll
    for (int st = 0; st < 4; ++st) {
        const int s = (w * 4 + st) * 16 + lm;
        #pragma unroll
        for (int dt = 0; dt < 4; ++dt) {
            const int d0 = dt * 16 + lk * 4;
            f32x4 hv = {0.f, 0.f, 0.f, 0.f};
            if (s < S) hv = *(const f32x4*)(h0 + (size_t)s * 64 + d0);
            hreg[st][dt] = hv;
            *(uint2*)&hB[s * 72 + d0] =
                make_uint2(pack2(hv.x, hv.y), pack2(hv.z, hv.w));
        }
    }

    // ---- MFMA for t=0 (wave-private hB rows; same-wave RAW is ordered) ----
    f32x4 acc[4][4];
    {
        short8v bfr[4][2];
        #pragma unroll
        for (int st = 0; st < 4; ++st) {
            const int s = (w * 4 + st) * 16 + lm;
            #pragma unroll
            for (int kc = 0; kc < 2; ++kc)
                bfr[st][kc] = *(const short8v*)&hB[s * 72 + kc * 32 + lk * 8];
        }
        #pragma unroll
        for (int dt = 0; dt < 4; ++dt)
            #pragma unroll
            for (int st = 0; st < 4; ++st) {
                f32x4 z = {0.f, 0.f, 0.f, 0.f};
                z = __builtin_amdgcn_mfma_f32_16x16x32_bf16(afr[dt][0], bfr[st][0], z, 0, 0, 0);
                z = __builtin_amdgcn_mfma_f32_16x16x32_bf16(afr[dt][1], bfr[st][1], z, 0, 0, 0);
                acc[dt][st] = z;
            }
    }
    __syncthreads();                               // eRow ready

    // ---- prologue: qP = {q[e0], q[e1]}; prefetch G[t=0] ----
    {
        const float q0 = (tid < S) ? q_matrix[(size_t)eRow[0] * S + tid] : 0.f;
        const float q1 = (tid < S) ? q_matrix[(size_t)eRow[1] * S + tid] : 0.f;
        qP[tid] = make_float2(q0, q1);
    }
    float g2v = 0.f, g3v = 0.f, g4v = 0.f;
    if (tid < 64) {
        g2v = G2[(b * L) * 64 + l];
        g3v = G3[(b * L) * 64 + l];
        g4v = G4it[(b * L) * 64 + l];
    }
    __syncthreads();                               // qP ready

    // ---- h_tilde_0 partials (2-round shfl -> red4) ----
    {
        f32x4 part[4];
        #pragma unroll
        for (int dt = 0; dt < 4; ++dt) part[dt] = f32x4{0.f, 0.f, 0.f, 0.f};
        #pragma unroll
        for (int st = 0; st < 4; ++st) {
            const int s = (w * 4 + st) * 16 + lm;
            const float qe = qP[s].x;
            #pragma unroll
            for (int dt = 0; dt < 4; ++dt) part[dt] += qe * hreg[st][dt];
        }
        #pragma unroll
        for (int dt = 0; dt < 4; ++dt)
            #pragma unroll
            for (int i = 0; i < 4; ++i) {
                float v = part[dt][i];
                v += __shfl_xor(v, 1); v += __shfl_xor(v, 2);
                part[dt][i] = v;
            }
        if ((lm & 3) == 0) {
            const int g = w * 4 + (lm >> 2);
            #pragma unroll
            for (int dt = 0; dt < 4; ++dt)
                *(f32x4*)&red4[g * 68 + dt * 16 + lk * 4] = part[dt];
        }
    }
    __syncthreads();                               // red4 ready (acts as b5)

    float qn_reg = 0.f;   // q[e_{t+2}] row element (loaded in-loop)

    // ---------------- 99 steps ----------------
    for (int t = 0; t < L - 1; ++t) {
        // P6 (wave 0): fold h_tilde_t -> htS, htH
        if (tid < 64) {
            float htd = 0.f;
            #pragma unroll
            for (int g = 0; g < 32; ++g) htd += red4[g * 68 + l];
            htS[l] = htd;
            htH[t * 64 + l] = htd;
        }
        __syncthreads();                           // b6

        // P1 (all): shift qP, issue next q load, gate partials
        if (t > 0) {
            const float2 qold = qP[tid];
            qP[tid] = make_float2(qold.y, qn_reg);
        }
        {
            const int tn = (t + 2 < L) ? t + 2 : L - 1;
            qn_reg = (tid < S) ? q_matrix[(size_t)eRow[tn] * S + tid] : 0.f;
        }
        {
            const f32x4 h4a = *(const f32x4*)&htS[kg * 8];
            const f32x4 h4b = *(const f32x4*)&htS[kg * 8 + 4];
            float p2 = 0.f, p3 = 0.f;
            #pragma unroll
            for (int j = 0; j < 4; ++j) {
                p2 += w2r[j] * h4a[j] + w2r[4 + j] * h4b[j];
                p3 += w3r[j] * h4a[j] + w3r[4 + j] * h4b[j];
            }
            red[kg * 64 + d]  = p2;
            red2[kg * 64 + d] = p3;
        }
        __syncthreads();                           // b1

        // P2 (wave 0): LG
        if (tid < 64) {
            float g2 = g2v, g3 = g3v;
            #pragma unroll
            for (int ww = 0; ww < 8; ++ww) { g2 += red[ww * 64 + d]; g3 += red2[ww * 64 + d]; }
            LGs[d] = sigm(g3) * (tanhf(g2) + 1.0f) * 0.5f;
        }
        __syncthreads();                           // b2

        // P3 (all): W4b @ LG partials
        {
            const f32x4 l4a = *(const f32x4*)&LGs[kg * 8];
            const f32x4 l4b = *(const f32x4*)&LGs[kg * 8 + 4];
            float pv = 0.f;
            #pragma unroll
            for (int j = 0; j < 4; ++j)
                pv += wbr[j] * l4a[j] + wbr[4 + j] * l4b[j];
            red[kg * 64 + d] = pv;
        }
        __syncthreads();                           // b3

        // P4 (wave 0): Vs fold + G prefetch for next step
        if (tid < 64) {
            float v = g4v;
            #pragma unroll
            for (int ww = 0; ww < 8; ++ww) v += red[ww * 64 + d];
            Vs[d] = v;
            g2v = G2[(b * L + t + 1) * 64 + l];
            g3v = G3[(b * L + t + 1) * 64 + l];
            g4v = G4it[(b * L + t + 1) * 64 + l];
        }
        __syncthreads();                           // b4

        // P5: epilogue (acc precomputed) -> h update, hB writes, partials
        float2 qv[4];
        #pragma unroll
        for (int st = 0; st < 4; ++st) qv[st] = qP[(w * 4 + st) * 16 + lm];

        f32x4 part[4];
        #pragma unroll
        for (int dt = 0; dt < 4; ++dt) part[dt] = f32x4{0.f, 0.f, 0.f, 0.f};

        #pragma unroll
        for (int dt = 0; dt < 4; ++dt) {
            const int d0 = dt * 16 + lk * 4;
            const f32x4 lg4 = *(const f32x4*)&LGs[d0];
            const f32x4 v4  = *(const f32x4*)&Vs[d0];
            #pragma unroll
            for (int st = 0; st < 4; ++st) {
                const int s = (w * 4 + st) * 16 + lm;
                const float qe = qv[st].x;
                const float qq = qv[st].y;
                const f32x4 a  = acc[dt][st];
                const f32x4 ho = hreg[st][dt];
                f32x4 hn;
                hn.x = qe * lg4.x + sigm(a.x + v4.x) * ho.x;
                hn.y = qe * lg4.y + sigm(a.y + v4.y) * ho.y;
                hn.z = qe * lg4.z + sigm(a.z + v4.z) * ho.z;
                hn.w = qe * lg4.w + sigm(a.w + v4.w) * ho.w;
                hreg[st][dt] = hn;
                *(uint2*)&hB[s * 72 + d0] =
                    make_uint2(pack2(hn.x, hn.y), pack2(hn.z, hn.w));
                part[dt] += qq * hn;
            }
        }

        // P5b: next step's MFMA (wave-private hB, no barrier needed)
        if (t < L - 2) {
            short8v bfr[4][2];
            #pragma unroll
            for (int st = 0; st < 4; ++st) {
                const int s = (w * 4 + st) * 16 + lm;
                #pragma unroll
                for (int kc = 0; kc < 2; ++kc)
                    bfr[st][kc] = *(const short8v*)&hB[s * 72 + kc * 32 + lk * 8];
            }
            #pragma unroll
            for (int dt = 0; dt < 4; ++dt)
                #pragma unroll
                for (int st = 0; st < 4; ++st) {
                    f32x4 z = {0.f, 0.f, 0.f, 0.f};
                    z = __builtin_amdgcn_mfma_f32_16x16x32_bf16(afr[dt][0], bfr[st][0], z, 0, 0, 0);
                    z = __builtin_amdgcn_mfma_f32_16x16x32_bf16(afr[dt][1], bfr[st][1], z, 0, 0, 0);
                    acc[dt][st] = z;
                }
        }

        // h_tilde_{t+1} partials: 2-round shfl, 16 writer lanes -> red4
        #pragma unroll
        for (int dt = 0; dt < 4; ++dt)
            #pragma unroll
            for (int i = 0; i < 4; ++i) {
                float v = part[dt][i];
                v += __shfl_xor(v, 1); v += __shfl_xor(v, 2);
                part[dt][i] = v;
            }
        if ((lm & 3) == 0) {
            const int g = w * 4 + (lm >> 2);
            #pragma unroll
            for (int dt = 0; dt < 4; ++dt)
                *(f32x4*)&red4[g * 68 + dt * 16 + lk * 4] = part[dt];
        }
        __syncthreads();                           // b5
    }

    // final fold: h_tilde_99 -> htH[99]
    if (tid < 64) {
        float htd = 0.f;
        #pragma unroll
        for (int g = 0; g < 32; ++g) htd += red4[g * 68 + l];
        htH[99 * 64 + l] = htd;
    }
    __syncthreads();
    // bulk write h_tilde history to global (coalesced)
    for (int i = tid; i < 100 * 64; i += 512)
        hthist[(size_t)(i >> 6) * (B * 64) + b * 64 + (i & 63)] = htH[i];
}

// ---------------- epilogue: y_t for t=1..99 --------------------------------
__global__ __launch_bounds__(64) void k_y(
    const float* __restrict__ hthist, const float* __restrict__ prey,
    const float* __restrict__ W5T, float* __restrict__ pred)
{
    __shared__ float HT[64];
    const int j = blockIdx.x + 1;    // 1..99
    const int b = blockIdx.y;
    const int d = threadIdx.x;
    HT[d] = hthist[(size_t)j * (B * 64) + b * 64 + d];
    __syncthreads();
    float acc = prey[(b * L + j) * 64 + d];
    #pragma unroll 8
    for (int k = 0; k < 64; ++k) acc += W5T[(128 + k) * 64 + d] * HT[k];
    float y = sigm(acc);
    #pragma unroll
    for (int m = 1; m < 64; m <<= 1) y += __shfl_xor(y, m);
    if (d == 0) pred[b * L + j] = y * (1.0f / 64.0f);
}

} // namespace

extern "C" void kernel_launch(void* const* d_in, const int* in_sizes, int n_in,
                              void* d_out, int out_size, void* d_ws, size_t ws_size,
                              hipStream_t stream)
{
    const int*   e_data   = (const int*)d_in[0];
    const int*   a_data   = (const int*)d_in[1];
    const int*   at_data  = (const int*)d_in[2];
    const int*   it_data  = (const int*)d_in[3];
    const float* q_matrix = (const float*)d_in[4];
    const float* h0       = (const float*)d_in[5];
    const float* e_embed  = (const float*)d_in[6];
    const float* at_embed = (const float*)d_in[7];
    const float* it_embed = (const float*)d_in[8];
    const float* W1 = (const float*)d_in[9];  const float* b1 = (const float*)d_in[10];
    const float* W2 = (const float*)d_in[11]; const float* b2 = (const float*)d_in[12];
    const float* W3 = (const float*)d_in[13]; const float* b3 = (const float*)d_in[14];
    const float* W4 = (const float*)d_in[15]; const float* b4 = (const float*)d_in[16];
    const float* W5 = (const float*)d_in[17]; const float* b5 = (const float*)d_in[18];
    float* pred = (float*)d_out;

    float* ws   = (float*)d_ws;
    float* W1T    = ws;                        // 16384
    float* W2T    = W1T    + 16384;            // 16384
    float* W3T    = W2T    + 16384;            // 16384
    float* W4T    = W3T    + 16384;            // 12288
    float* W5T    = W4T    + 12288;            // 12288
    float* allL   = W5T    + 12288;            // 204800
    float* G2     = allL   + 204800;
    float* G3     = G2     + 204800;
    float* G4it   = G3     + 204800;
    float* prey   = G4it   + 204800;
    float* hthist = prey   + 204800;           // L*B*64 = 204800
    // total ~5.2 MB

    hipLaunchKernelGGL(k_init, dim3(64), dim3(256), 0, stream,
                       W1, W2, W3, W4, W5, W1T, W2T, W3T, W4T, W5T, pred);
    hipLaunchKernelGGL(k_all_learning, dim3(B * L / 4), dim3(256), 0, stream,
                       e_data, a_data, at_data, e_embed, at_embed, W1T, b1, allL);
    hipLaunchKernelGGL(k_pre, dim3(B * L / 4), dim3(256), 0, stream,
                       e_data, it_data, e_embed, it_embed, allL,
                       W2T, W3T, W4T, W5T, b2, b3, b4, b5, G2, G3, G4it, prey);
    hipLaunchKernelGGL(k_steps, dim3(B), dim3(512), 0, stream,
                       G2, G3, G4it, W2, W3, W4, q_matrix, e_data, h0, hthist);
    hipLaunchKernelGGL(k_y, dim3(L - 1, B), dim3(64), 0, stream,
                       hthist, prey, W5T, pred);
}